// Round 8
// baseline (400.910 us; speedup 1.0000x reference)
//
#include <hip/hip_runtime.h>

// Shapes (fixed): B=4, N=256, D_MODEL=256, D_EDGE=64, H=8, C=32
// workspace layout (float offsets)
#define OQ  0
#define OK  262144   // KT[b][hc][j]  (K stored TRANSPOSED)
#define OV  524288
#define OS  786432   // skip = x@W_s + b_s
#define OWT 1048576  // WeT[hc][d] = W_e[d][hc]

static __device__ __forceinline__ float4 ld4(const float* p) {
    return *reinterpret_cast<const float4*>(p);
}

// ---------------------------------------------------------------------------
// Kernel 1: Q/KT/V/skip projections. FIX vs round 4-7: xs stride 256 -> 260.
// (xs[tr*256+d] with tr=t>>4 was a 16-way bank conflict: 16 addrs, all bank
// d%32. stride 260 -> (tr*4+d)%32 spans 8 banks, 2-way = free.)
// ---------------------------------------------------------------------------
__global__ __launch_bounds__(256) void fused_qkvs(
    const float* __restrict__ x,
    const float* __restrict__ Wq, const float* __restrict__ bq,
    const float* __restrict__ Wk, const float* __restrict__ bk,
    const float* __restrict__ Wv, const float* __restrict__ bv,
    const float* __restrict__ Wsk, const float* __restrict__ bsk,
    const float* __restrict__ We, float* __restrict__ ws)
{
    const int t = threadIdx.x;
    const int bid = blockIdx.x;

    if (bid == 1024) {   // W_e (64x256) -> WeT[hc*64+d]
        #pragma unroll
        for (int k = 0; k < 64; ++k) {
            int o = k * 256 + t;
            ws[OWT + o] = We[(o & 63) * 256 + (o >> 6)];
        }
        return;
    }

    __shared__ float xs[16 * 260];   // padded stride 260 (1040B = 65x16B, f4-ok)
    __shared__ float xp[64 * 17];

    const int mat = bid >> 8;
    const int sub = bid & 255;
    const int r0 = (sub >> 2) * 16;
    const int c0 = (sub & 3) * 64;
    const float* W; const float* bb;
    if      (mat == 0) { W = Wq;  bb = bq;  }
    else if (mat == 1) { W = Wk;  bb = bk;  }
    else if (mat == 2) { W = Wv;  bb = bv;  }
    else               { W = Wsk; bb = bsk; }

    {   // stage x tile (coalesced f4), padded rows
        const float4* xsrc = reinterpret_cast<const float4*>(x + r0 * 256);
        #pragma unroll
        for (int k = 0; k < 4; ++k) {
            int q = t + k * 256;             // f4 idx
            int r = q >> 6, cq = q & 63;
            *reinterpret_cast<float4*>(&xs[r * 260 + cq * 4]) = xsrc[q];
        }
    }
    __syncthreads();

    const int tr = t >> 4;
    const int tc = t & 15;
    float a0 = 0.f, a1 = 0.f, a2 = 0.f, a3 = 0.f;
    #pragma unroll 8
    for (int d = 0; d < 256; ++d) {
        float4 wv = ld4(&W[d * 256 + c0 + tc * 4]);   // 256B/group, L2-hot
        float xv = xs[tr * 260 + d];                  // 2-way max (free)
        a0 += xv * wv.x; a1 += xv * wv.y; a2 += xv * wv.z; a3 += xv * wv.w;
    }
    float4 bv4 = ld4(&bb[c0 + tc * 4]);
    a0 += bv4.x; a1 += bv4.y; a2 += bv4.z; a3 += bv4.w;

    if (mat != 1) {
        float* outp = ws + (mat == 0 ? OQ : (mat == 2 ? OV : OS));
        float4 o = make_float4(a0, a1, a2, a3);
        *reinterpret_cast<float4*>(&outp[(r0 + tr) * 256 + c0 + tc * 4]) = o;
    } else {
        xp[(tc * 4 + 0) * 17 + tr] = a0;
        xp[(tc * 4 + 1) * 17 + tr] = a1;
        xp[(tc * 4 + 2) * 17 + tr] = a2;
        xp[(tc * 4 + 3) * 17 + tr] = a3;
        __syncthreads();
        const int b = r0 >> 8, rb0 = r0 & 255;
        float* KT = ws + OK + b * 65536;
        const int rl = t & 15;
        #pragma unroll
        for (int q2 = 0; q2 < 4; ++q2) {
            int hcl = q2 * 16 + (t >> 4);
            KT[(c0 + hcl) * 256 + rb0 + rl] = xp[hcl * 17 + rl];
        }
    }
}

// ---------------------------------------------------------------------------
// Kernel 2: HEAD-SPLIT fused edge attention. 2048 blocks = (row, head-half).
// Each block: 4 heads x all 256 j. Softmax per-head is block-local -> plain
// 2-pass softmax, NO online rescale, 8 barriers total. All global streams
// coalesced; QE reads own edge row (wave walks 16KB, L1-resident).
// ---------------------------------------------------------------------------
__global__ __launch_bounds__(256) void fused_attn2(
    const float* __restrict__ edge, const unsigned char* __restrict__ mask,
    const float* __restrict__ We, const float* __restrict__ ws,
    float* __restrict__ out)
{
    __shared__ float qs[128];        // q slice (4 heads)
    __shared__ float Ps[256];        // P[h2][64]; reused as As after b7
    __shared__ float pt[4 * 260];    // p[h2][j], padded stride (2-way max)
    __shared__ float red[32];        // wave partials: [0..15] max, [16..31] sum
    __shared__ float mx2[4], sm2[4];
    __shared__ float avred[8 * 136]; // AV js-partials, padded stride
    __shared__ float ared[4 * 260];  // A js4-partials, padded stride
    __shared__ int mflag;            // 1 = byte mask, 0 = int32 mask

    const int t   = threadIdx.x;
    const int row = blockIdx.x >> 1;     // b*256 + i
    const int hp  = blockIdx.x & 1;
    const int b   = row >> 8;
    const int cb  = hp * 128;            // d_model col base (4 heads)
    const float* erow = edge + (size_t)row * (256 * 64);
    const float scale = 0.17677669529663687f;   // 1/sqrt(32)

    if (t == 0) mflag = 0;
    if (t < 128) qs[t] = ws[OQ + row * 256 + cb + t];
    __syncthreads();   // b1

    {   // mask layout detect (first 4KB): int32 0/1 has zero bytes at off%4!=0
        int found = 0;
        #pragma unroll
        for (int k = 0; k < 16; ++k)
            if ((k & 3) != 0 && mask[t * 16 + k]) found = 1;
        if (found) mflag = 1;            // benign same-value race
    }
    {   // Ps[h2][d] = sum_c q[h2*32+c] * WeT[(cb+h2*32+c)*64+d]
        const int h2 = t >> 6, d = t & 63;
        const float* WT = ws + OWT;
        float pa = 0.f, pb = 0.f;
        #pragma unroll
        for (int c = 0; c < 32; c += 2) {
            pa += qs[h2 * 32 + c]     * WT[(cb + h2 * 32 + c) * 64 + d];
            pb += qs[h2 * 32 + c + 1] * WT[(cb + h2 * 32 + c + 1) * 64 + d];
        }
        Ps[h2 * 64 + d] = pa + pb;
    }
    __syncthreads();   // b2 (Ps + mflag ready)
    const int MB = mflag;

    // ---- scores: thread t = j; s[h2] for 4 heads ----
    float s[4];
    bool mk;
    {
        const int j = t;
        float a0[4] = {}, a1[4] = {};
        const float* ktb = ws + OK + b * 65536 + j;
        #pragma unroll
        for (int c = 0; c < 32; c += 2) {
            #pragma unroll
            for (int h2 = 0; h2 < 4; ++h2) {
                a0[h2] += qs[h2 * 32 + c]     * ktb[(cb + h2 * 32 + c) * 256];
                a1[h2] += qs[h2 * 32 + c + 1] * ktb[(cb + h2 * 32 + c + 1) * 256];
            }
        }
        #pragma unroll
        for (int k = 0; k < 16; ++k) {
            float4 ev = ld4(&erow[j * 64 + k * 4]);   // own row, L1-resident walk
            #pragma unroll
            for (int h2 = 0; h2 < 4; ++h2) {
                float4 pv = ld4(&Ps[h2 * 64 + k * 4]); // 4-addr broadcast
                a0[h2] += ev.x * pv.x + ev.y * pv.y;
                a1[h2] += ev.z * pv.z + ev.w * pv.w;
            }
        }
        mk = MB ? (mask[row * 256 + j] != 0)
                : (reinterpret_cast<const int*>(mask)[row * 256 + j] != 0);
        #pragma unroll
        for (int h2 = 0; h2 < 4; ++h2)
            s[h2] = mk ? (a0[h2] + a1[h2]) * scale : -1e30f;
    }

    // ---- softmax (plain, 2-level reduce) ----
    const int wv = t >> 6;
    {
        float m[4] = { s[0], s[1], s[2], s[3] };
        #pragma unroll
        for (int off = 32; off; off >>= 1) {
            #pragma unroll
            for (int h2 = 0; h2 < 4; ++h2) m[h2] = fmaxf(m[h2], __shfl_xor(m[h2], off));
        }
        if ((t & 63) == 0) {
            #pragma unroll
            for (int h2 = 0; h2 < 4; ++h2) red[wv * 4 + h2] = m[h2];
        }
    }
    __syncthreads();   // b3
    if (t < 4) mx2[t] = fmaxf(fmaxf(red[t], red[4 + t]), fmaxf(red[8 + t], red[12 + t]));
    __syncthreads();   // b4
    {
        float r[4];
        #pragma unroll
        for (int h2 = 0; h2 < 4; ++h2) {
            float pv = mk ? __expf(s[h2] - mx2[h2]) : 0.f;  // masked exactly 0
            pt[h2 * 260 + t] = pv;
            r[h2] = pv;
        }
        #pragma unroll
        for (int off = 32; off; off >>= 1) {
            #pragma unroll
            for (int h2 = 0; h2 < 4; ++h2) r[h2] += __shfl_xor(r[h2], off);
        }
        if ((t & 63) == 0) {
            #pragma unroll
            for (int h2 = 0; h2 < 4; ++h2) red[16 + wv * 4 + h2] = r[h2];
        }
    }
    __syncthreads();   // b5
    if (t < 4) sm2[t] = (red[16 + t] + red[20 + t]) + (red[24 + t] + red[28 + t]);
    __syncthreads();   // b6 (pt + sm2 ready)

    // ---- AV: (hcq = t&31 f4-col, js = t>>5); V f4-coalesced ----
    float4 accV = make_float4(0.f, 0.f, 0.f, 0.f);
    {
        const int hcq = t & 31, js = t >> 5;
        const int h2 = hcq >> 3;
        const float* vp = ws + OV + ((size_t)(b << 8) + js * 32) * 256 + cb + hcq * 4;
        const float* pp = pt + h2 * 260 + js * 32;
        #pragma unroll
        for (int jj = 0; jj < 32; ++jj) {
            float4 vv = ld4(vp); vp += 256;           // 512B/js-group coalesced
            float pv = pp[jj];                        // 2-way max (padded)
            accV.x += pv * vv.x; accV.y += pv * vv.y;
            accV.z += pv * vv.z; accV.w += pv * vv.w;
        }
    }
    // ---- A[h2][d]: (d = t&63, js4 = t>>6); edge coalesced 256B/wave, L2-hot ----
    float aA[4] = {};
    {
        const int d = t & 63, js4 = t >> 6;
        #pragma unroll 4
        for (int jj = 0; jj < 64; ++jj) {
            int j = js4 * 64 + jj;
            float ev = erow[j * 64 + d];
            #pragma unroll
            for (int h2 = 0; h2 < 4; ++h2) aA[h2] += pt[h2 * 260 + j] * ev;  // broadcast
        }
    }
    {   // store partials
        const int hcq = t & 31, js = t >> 5;
        *reinterpret_cast<float4*>(&avred[js * 136 + hcq * 4]) = accV;
        const int d = t & 63, js4 = t >> 6;
        #pragma unroll
        for (int h2 = 0; h2 < 4; ++h2) ared[js4 * 260 + h2 * 64 + d] = aA[h2];
    }
    __syncthreads();   // b7

    // ---- reduce A into Ps (alias; Ps dead after scores) ----
    Ps[t] = (ared[t] + ared[260 + t]) + (ared[520 + t] + ared[780 + t]);
    __syncthreads();   // b8

    // ---- epilogue (t<128): reduce AV, outE = A@We slice, normalize + skip ----
    if (t < 128) {
        float v = 0.f;
        #pragma unroll
        for (int js = 0; js < 8; ++js) v += avred[js * 136 + t];  // stride-1 lanes
        const int h2 = t >> 5;
        float e0 = 0.f, e1 = 0.f, e2 = 0.f, e3 = 0.f;
        #pragma unroll
        for (int d4 = 0; d4 < 16; ++d4) {
            float4 av = ld4(&Ps[h2 * 64 + d4 * 4]);   // 2-addr broadcast
            e0 += av.x * We[(d4 * 4 + 0) * 256 + cb + t];  // coalesced
            e1 += av.y * We[(d4 * 4 + 1) * 256 + cb + t];
            e2 += av.z * We[(d4 * 4 + 2) * 256 + cb + t];
            e3 += av.w * We[(d4 * 4 + 3) * 256 + cb + t];
        }
        float denom = sm2[h2];
        float inv = denom > 0.f ? 1.f / denom : 0.f;  // nan_to_num for masked rows
        out[row * 256 + cb + t] =
            (v + (e0 + e1) + (e2 + e3)) * inv + ws[OS + row * 256 + cb + t];
    }
}

// ---------------------------------------------------------------------------
extern "C" void kernel_launch(void* const* d_in, const int* in_sizes, int n_in,
                              void* d_out, int out_size, void* d_ws, size_t ws_size,
                              hipStream_t stream) {
    const float* x    = (const float*)d_in[0];
    const float* edge = (const float*)d_in[1];
    const unsigned char* mask = (const unsigned char*)d_in[2];  // layout auto-detected
    const float* Wq = (const float*)d_in[3];
    const float* bq = (const float*)d_in[4];
    const float* Wk = (const float*)d_in[5];
    const float* bk = (const float*)d_in[6];
    const float* Wv = (const float*)d_in[7];
    const float* bv = (const float*)d_in[8];
    const float* We = (const float*)d_in[9];
    const float* Wsk = (const float*)d_in[10];
    const float* bsk = (const float*)d_in[11];
    float* out = (float*)d_out;
    float* ws  = (float*)d_ws;

    fused_qkvs<<<1025, 256, 0, stream>>>(x, Wq, bq, Wk, bk, Wv, bv, Wsk, bsk, We, ws);
    fused_attn2<<<2048, 256, 0, stream>>>(edge, mask, We, ws, out);
}

// Round 13
// 170.883 us; speedup vs baseline: 2.3461x; 2.3461x over previous
//
#include <hip/hip_runtime.h>

// Shapes (fixed): B=4, N=256, D_MODEL=256, D_EDGE=64, H=8, C=32
// workspace layout (float offsets) — 4.06 MB total (proven budget)
#define OQ  0
#define OK  262144   // KT[b][hc][j]  (K stored TRANSPOSED)
#define OV  524288
#define OS  786432   // skip = x@W_s + b_s
#define OWT 1048576  // WeT[hc][d] = W_e[d][hc]

static __device__ __forceinline__ float4 ld4(const float* p) {
    return *reinterpret_cast<const float4*>(p);
}

// ---------------------------------------------------------------------------
// Kernel 1: proper tiled GEMM for Q/KT/V/skip. grid = 513 x 256.
// bid<512: mat = bid>>7 (0=Q,1=K->KT,2=V,3=S); sub = bid&127:
//   rowtile rt = sub>>2 (32 rows), coltile ct = sub&3 (64 cols).
// K-loop in 4 chunks of 64, x-tile AND W-tile staged in LDS.
// Per thread: 2 rows x 4 cols, 8 FMA per (1 b128 + 2 b32) LDS reads.
// bid==512: W_e transpose (LDS-tiled, coalesced both sides).
// ---------------------------------------------------------------------------
__global__ __launch_bounds__(256) void gemm_qkvs(
    const float* __restrict__ x,
    const float* __restrict__ Wq, const float* __restrict__ bq,
    const float* __restrict__ Wk, const float* __restrict__ bk,
    const float* __restrict__ Wv, const float* __restrict__ bv,
    const float* __restrict__ Wsk, const float* __restrict__ bsk,
    const float* __restrict__ We, float* __restrict__ ws)
{
    const int t = threadIdx.x;
    const int bid = blockIdx.x;

    __shared__ float xs[32 * 68];    // x chunk (also KT-bounce scratch 64x33)
    __shared__ float wsb[64 * 68];   // W chunk

    if (bid == 512) {   // We (64x256) -> WeT[hc*64+d], 4 chunks of 64 hc
        for (int cc = 0; cc < 4; ++cc) {
            #pragma unroll
            for (int m = 0; m < 4; ++m) {
                int q = m * 256 + t;            // f4 idx
                int d = q >> 4, c4 = q & 15;
                *reinterpret_cast<float4*>(&wsb[d * 68 + c4 * 4]) =
                    ld4(&We[d * 256 + cc * 64 + c4 * 4]);   // coalesced
            }
            __syncthreads();
            #pragma unroll
            for (int m = 0; m < 4; ++m) {
                int q = m * 256 + t;
                int hc = q >> 4, dq = q & 15;
                float4 o;
                o.x = wsb[(dq * 4 + 0) * 68 + hc];
                o.y = wsb[(dq * 4 + 1) * 68 + hc];
                o.z = wsb[(dq * 4 + 2) * 68 + hc];
                o.w = wsb[(dq * 4 + 3) * 68 + hc];
                *reinterpret_cast<float4*>(&ws[OWT + (cc * 64 + hc) * 64 + dq * 4]) = o;
            }
            __syncthreads();
        }
        return;
    }

    const int mat = bid >> 7;
    const int sub = bid & 127;
    const int r0 = (sub >> 2) * 32;   // global row base (32 | 256: no batch straddle)
    const int c0 = (sub & 3) * 64;
    const float* W; const float* bb;
    if      (mat == 0) { W = Wq;  bb = bq;  }
    else if (mat == 1) { W = Wk;  bb = bk;  }
    else if (mat == 2) { W = Wv;  bb = bv;  }
    else               { W = Wsk; bb = bsk; }

    const int tc = t & 15;            // col f4 0..15
    const int tr = t >> 4;            // row pair 0..15
    float acc[2][4] = {};

    for (int kc = 0; kc < 4; ++kc) {
        const int k0 = kc * 64;
        #pragma unroll
        for (int m = 0; m < 2; ++m) { // x chunk 32x64 = 512 f4
            int q = m * 256 + t;
            int r = q >> 4, c4 = q & 15;
            *reinterpret_cast<float4*>(&xs[r * 68 + c4 * 4]) =
                ld4(&x[(r0 + r) * 256 + k0 + c4 * 4]);
        }
        #pragma unroll
        for (int m = 0; m < 4; ++m) { // W chunk 64x64 = 1024 f4
            int q = m * 256 + t;
            int r = q >> 4, c4 = q & 15;
            *reinterpret_cast<float4*>(&wsb[r * 68 + c4 * 4]) =
                ld4(&W[(k0 + r) * 256 + c0 + c4 * 4]);
        }
        __syncthreads();

        #pragma unroll 8
        for (int k = 0; k < 64; ++k) {
            float4 w4 = ld4(&wsb[k * 68 + tc * 4]);    // 2-way max (free)
            float x0 = xs[(tr * 2 + 0) * 68 + k];      // 4-addr broadcast
            float x1 = xs[(tr * 2 + 1) * 68 + k];
            acc[0][0] += x0 * w4.x; acc[0][1] += x0 * w4.y;
            acc[0][2] += x0 * w4.z; acc[0][3] += x0 * w4.w;
            acc[1][0] += x1 * w4.x; acc[1][1] += x1 * w4.y;
            acc[1][2] += x1 * w4.z; acc[1][3] += x1 * w4.w;
        }
        __syncthreads();
    }

    float4 bv4 = ld4(&bb[c0 + tc * 4]);
    #pragma unroll
    for (int rr = 0; rr < 2; ++rr) {
        acc[rr][0] += bv4.x; acc[rr][1] += bv4.y;
        acc[rr][2] += bv4.z; acc[rr][3] += bv4.w;
    }

    if (mat != 1) {
        float* outp = ws + (mat == 0 ? OQ : (mat == 2 ? OV : OS));
        #pragma unroll
        for (int rr = 0; rr < 2; ++rr) {
            float4 o = make_float4(acc[rr][0], acc[rr][1], acc[rr][2], acc[rr][3]);
            *reinterpret_cast<float4*>(&outp[(r0 + tr * 2 + rr) * 256 + c0 + tc * 4]) = o;
        }
    } else {
        // KT[b][hc][j]: bounce via xs-scratch (64 hc x 33) for coalesced stores
        float* xp = xs;
        #pragma unroll
        for (int rr = 0; rr < 2; ++rr)
            #pragma unroll
            for (int cc = 0; cc < 4; ++cc)
                xp[(tc * 4 + cc) * 33 + tr * 2 + rr] = acc[rr][cc];
        __syncthreads();
        const int b = r0 >> 8, rb = r0 & 255;
        float* KT = ws + OK + b * 65536;
        #pragma unroll
        for (int m = 0; m < 8; ++m) {
            int idx = m * 256 + t;
            int hc = idx >> 5, j = idx & 31;
            KT[(c0 + hc) * 256 + rb + j] = xp[hc * 33 + j];
        }
    }
}

// ---------------------------------------------------------------------------
// Kernel 2: fused edge attention — round-2 structure (proven 97us, 40 VGPR,
// 39% occ) with ONE change: QK reads coalesced KT columns instead of the
// per-lane K-row gather. Unrolls capped to avoid round-8's spill disaster.
// One block per (b,i) row, thread t = source j.
// ---------------------------------------------------------------------------
__global__ __launch_bounds__(256) void fused_attn3(
    const float* __restrict__ edge, const unsigned char* __restrict__ mask,
    const float* __restrict__ We, const float* __restrict__ ws,
    float* __restrict__ out)
{
    __shared__ float qs[256];       // Q row
    __shared__ float Ps[512];       // P[h][d]
    __shared__ float pt[8 * 260];   // scores then p, [h][j]
    __shared__ float As[512];       // A[h][d]
    __shared__ float mx[8];
    __shared__ float sm[8];
    __shared__ int mflag;           // 1 = byte mask, 0 = int32 mask

    const float* Q  = ws + OQ;
    const float* KT = ws + OK;
    const float* V  = ws + OV;
    const float* SK = ws + OS;
    const float* WT = ws + OWT;

    const int t   = threadIdx.x;    // = source node j
    const int row = blockIdx.x;     // b*256 + i
    const int b   = row >> 8;
    const float* erow = edge + (size_t)row * (256 * 64);
    const float scale = 0.17677669529663687f;   // 1/sqrt(32)

    if (t == 0) mflag = 0;
    qs[t] = Q[row * 256 + t];
    __syncthreads();

    {   // mask layout detect: int32 0/1 has zero bytes at off%4!=0
        int found = 0;
        #pragma unroll
        for (int k = 0; k < 16; ++k)
            if ((k & 3) != 0 && mask[t * 16 + k]) found = 1;
        if (found) mflag = 1;       // benign same-value race
    }

    // P[h][d] = sum_c q[h*32+c] * WeT[(h*32+c)*64+d]  (coalesced, L2-hot)
    #pragma unroll
    for (int rep = 0; rep < 2; ++rep) {
        int idx = t + rep * 256;
        int h = idx >> 6, d = idx & 63;
        float pa = 0.f, pb = 0.f;
        #pragma unroll 8
        for (int c = 0; c < 32; c += 2) {
            pa += qs[h * 32 + c]     * WT[(h * 32 + c) * 64 + d];
            pb += qs[h * 32 + c + 1] * WT[(h * 32 + c + 1) * 64 + d];
        }
        Ps[idx] = pa + pb;
    }
    __syncthreads();
    const int MB = mflag;
    const bool mk = MB ? (mask[row * 256 + t] != 0)
                       : (reinterpret_cast<const int*>(mask)[row * 256 + t] != 0);

    // ---- scores for j = t: QK via coalesced KT columns + QE via own edge row ----
    float s[8] = {};
    {
        const float* ktb = KT + b * 65536 + t;   // lane t contiguous -> coalesced
        #pragma unroll 4
        for (int c = 0; c < 32; ++c) {
            #pragma unroll
            for (int h = 0; h < 8; ++h)
                s[h] += qs[h * 32 + c] * ktb[(h * 32 + c) * 256];
        }
        #pragma unroll 2
        for (int k = 0; k < 16; ++k) {
            float4 ev = ld4(&erow[t * 64 + k * 4]);   // lane-private row, L1-hot
            #pragma unroll
            for (int h = 0; h < 8; ++h) {
                float4 pv = ld4(&Ps[h * 64 + k * 4]); // broadcast
                s[h] += ev.x * pv.x + ev.y * pv.y + ev.z * pv.z + ev.w * pv.w;
            }
        }
        #pragma unroll
        for (int h = 0; h < 8; ++h) {
            s[h] *= scale;
            if (!mk) s[h] = -1e30f;
            pt[h * 260 + t] = s[h];
        }
    }
    __syncthreads();

    // ---- per-head max over j ----
    {
        int h = t >> 5, l = t & 31;
        float m = -1e30f;
        #pragma unroll
        for (int k = 0; k < 8; ++k) m = fmaxf(m, pt[h * 260 + l + k * 32]);
        #pragma unroll
        for (int off = 16; off; off >>= 1) m = fmaxf(m, __shfl_xor(m, off));
        if (l == 0) mx[h] = m;
    }
    __syncthreads();

    // ---- p = exp(s - max), masked lanes exactly 0 ----
    #pragma unroll
    for (int h = 0; h < 8; ++h)
        pt[h * 260 + t] = mk ? __expf(s[h] - mx[h]) : 0.f;
    __syncthreads();

    // ---- per-head sum over j ----
    {
        int h = t >> 5, l = t & 31;
        float a = 0.f;
        #pragma unroll
        for (int k = 0; k < 8; ++k) a += pt[h * 260 + l + k * 32];
        #pragma unroll
        for (int off = 16; off; off >>= 1) a += __shfl_xor(a, off);
        if (l == 0) sm[h] = a;      // sum==0 => fully masked row
    }
    __syncthreads();

    // ---- out_V[h,c]: thread t = h*32+c; 4-acc ILP; V coalesced over t ----
    float accV;
    {
        int h = t >> 5;
        const float* vcol = V + (b << 8) * 256 + t;
        float v0 = 0.f, v1 = 0.f, v2 = 0.f, v3 = 0.f;
        #pragma unroll 4
        for (int j4 = 0; j4 < 64; ++j4) {
            float4 pv = ld4(&pt[h * 260 + j4 * 4]);     // broadcast
            v0 += pv.x * vcol[(j4 * 4 + 0) * 256];
            v1 += pv.y * vcol[(j4 * 4 + 1) * 256];
            v2 += pv.z * vcol[(j4 * 4 + 2) * 256];
            v3 += pv.w * vcol[(j4 * 4 + 3) * 256];
        }
        accV = (v0 + v1) + (v2 + v3);
    }

    // ---- A[h][d] = sum_j p[j,h]*edge[j,d]; edge coalesced (L2-hot), 8-acc ----
    {
        int h2 = t >> 6, d = t & 63;
        float a00=0.f,a01=0.f,a02=0.f,a03=0.f,a10=0.f,a11=0.f,a12=0.f,a13=0.f;
        #pragma unroll 4
        for (int j4 = 0; j4 < 64; ++j4) {
            float4 p0 = ld4(&pt[h2 * 260 + j4 * 4]);
            float4 p1 = ld4(&pt[(h2 + 4) * 260 + j4 * 4]);
            float e0 = erow[(j4 * 4 + 0) * 64 + d];
            float e1 = erow[(j4 * 4 + 1) * 64 + d];
            float e2 = erow[(j4 * 4 + 2) * 64 + d];
            float e3 = erow[(j4 * 4 + 3) * 64 + d];
            a00 += p0.x * e0; a01 += p0.y * e1; a02 += p0.z * e2; a03 += p0.w * e3;
            a10 += p1.x * e0; a11 += p1.y * e1; a12 += p1.z * e2; a13 += p1.w * e3;
        }
        As[h2 * 64 + d]       = (a00 + a01) + (a02 + a03);
        As[(h2 + 4) * 64 + d] = (a10 + a11) + (a12 + a13);
    }
    __syncthreads();

    // ---- out_E[h,c] = sum_d A[h,d]*W_e[d,hc]; normalize + skip ----
    {
        int h = t >> 5;
        float e0 = 0.f, e1 = 0.f, e2 = 0.f, e3 = 0.f;
        #pragma unroll
        for (int d4 = 0; d4 < 16; ++d4) {
            float4 av = ld4(&As[h * 64 + d4 * 4]);      // broadcast
            e0 += av.x * We[(d4 * 4 + 0) * 256 + t];    // coalesced
            e1 += av.y * We[(d4 * 4 + 1) * 256 + t];
            e2 += av.z * We[(d4 * 4 + 2) * 256 + t];
            e3 += av.w * We[(d4 * 4 + 3) * 256 + t];
        }
        float accE = (e0 + e1) + (e2 + e3);
        float denom = sm[t >> 5];
        float inv = denom > 0.f ? 1.f / denom : 0.f;    // nan_to_num
        out[row * 256 + t] = (accV + accE) * inv + SK[row * 256 + t];
    }
}

// ---------------------------------------------------------------------------
extern "C" void kernel_launch(void* const* d_in, const int* in_sizes, int n_in,
                              void* d_out, int out_size, void* d_ws, size_t ws_size,
                              hipStream_t stream) {
    const float* x    = (const float*)d_in[0];
    const float* edge = (const float*)d_in[1];
    const unsigned char* mask = (const unsigned char*)d_in[2];  // layout auto-detected
    const float* Wq = (const float*)d_in[3];
    const float* bq = (const float*)d_in[4];
    const float* Wk = (const float*)d_in[5];
    const float* bk = (const float*)d_in[6];
    const float* Wv = (const float*)d_in[7];
    const float* bv = (const float*)d_in[8];
    const float* We = (const float*)d_in[9];
    const float* Wsk = (const float*)d_in[10];
    const float* bsk = (const float*)d_in[11];
    float* out = (float*)d_out;
    float* ws  = (float*)d_ws;

    gemm_qkvs<<<513, 256, 0, stream>>>(x, Wq, bq, Wk, bk, Wv, bv, Wsk, bsk, We, ws);
    fused_attn3<<<1024, 256, 0, stream>>>(edge, mask, We, ws, out);
}